// Round 14
// baseline (114.274 us; speedup 1.0000x reference)
//
#include <hip/hip_runtime.h>
#include <stdint.h>

typedef signed char s8;
typedef int i32x4 __attribute__((ext_vector_type(4)));

#define B_HALF 4096
#define NROWS 8192
#define DCOL 512
#define BM 128
#define TT 64            // 8192/128
#define NTILES 2080      // TT*(TT+1)/2
#define KT 8             // 512 / 64 bytes per K-step
#define QSCALE 32.0f
#define INV_S2 (1.0f / 1024.0f)
#define PREP_BLOCKS (NROWS / 16)   // 512
#define NREP 8

// ---------- kernel Z: zero the 20.5 KB accumulator region (colsum_rep+sumsq_rep+counter) ----------
__global__ void zero_kernel(uint4* __restrict__ p) {
  int t = threadIdx.x;
#pragma unroll
  for (int i = 0; i < 5; ++i)
    p[t + i * 256] = (uint4){0u, 0u, 0u, 0u};   // 5 * 256 * 16 B = 20480 B
}

// ---------- kernel A: quantize + sqq + 8-replica colsum/sumsq (no tail) ----------
__global__ __launch_bounds__(256) void prep_kernel(const float* __restrict__ src,
    const float* __restrict__ tgt, s8* __restrict__ qp,
    float* __restrict__ sqq, float* __restrict__ colsum_rep,
    double* __restrict__ sumsq_rep) {
  __shared__ float cs[4][DCOL];
  __shared__ double redd[4];
  int tid = threadIdx.x;
  int lane = tid & 63, wid = tid >> 6;
  float cpart[8] = {0.f,0.f,0.f,0.f,0.f,0.f,0.f,0.f};
  float myssq = 0.f;
  int row0 = blockIdx.x * 16;
#pragma unroll
  for (int r = 0; r < 4; ++r) {
    int row = row0 + r * 4 + wid;
    const float* x = (row < B_HALF) ? (src + (size_t)row * DCOL)
                                    : (tgt + (size_t)(row - B_HALF) * DCOL);
    float4 v0 = *reinterpret_cast<const float4*>(x + lane * 8);
    float4 v1 = *reinterpret_cast<const float4*>(x + lane * 8 + 4);
    float vals[8] = {v0.x, v0.y, v0.z, v0.w, v1.x, v1.y, v1.z, v1.w};
    union { s8 c[8]; uint2 u; } pu;
    int iq = 0;
#pragma unroll
    for (int q = 0; q < 8; ++q) {
      float f = vals[q];
      myssq += f * f;
      cpart[q] += f;
      int k = __float2int_rn(fminf(fmaxf(f * QSCALE, -127.f), 127.f));
      pu.c[q] = (s8)k;
      iq += k * k;
    }
    *reinterpret_cast<uint2*>(qp + (size_t)row * DCOL + lane * 8) = pu.u;
#pragma unroll
    for (int o = 32; o > 0; o >>= 1) iq += __shfl_down(iq, o);
    if (lane == 0) sqq[row] = (float)iq * INV_S2;   // exact: iq < 2^23
  }
  double dssq = (double)myssq;
#pragma unroll
  for (int o = 32; o > 0; o >>= 1) dssq += __shfl_down(dssq, o);
  if (lane == 0) redd[wid] = dssq;
#pragma unroll
  for (int q = 0; q < 8; ++q) cs[wid][lane * 8 + q] = cpart[q];
  __syncthreads();
  // 8-replica accumulation (R13-proven); visibility to next kernel via launch boundary
  int rep = (blockIdx.x & (NREP - 1)) * DCOL;
  int c = tid;
  atomicAdd(&colsum_rep[rep + c],
            cs[0][c] + cs[1][c] + cs[2][c] + cs[3][c]);
  atomicAdd(&colsum_rep[rep + c + 256],
            cs[0][c + 256] + cs[1][c + 256] + cs[2][c + 256] + cs[3][c + 256]);
  if (tid == 0)
    atomicAdd(&sumsq_rep[blockIdx.x & (NREP - 1)],
              redd[0] + redd[1] + redd[2] + redd[3]);
}

// ---------- kernel B: 128x128 triangle i8 MFMA Gram, BK=64 dbl-row, 3-buf counted vmcnt
// (R13-proven core) + fused per-block bandwidth prologue + fused R8-style finalize ----------
#define GLDS(gptr, lptr) __builtin_amdgcn_global_load_lds( \
    (const __attribute__((address_space(1))) void*)(gptr), \
    (__attribute__((address_space(3))) void*)(lptr), 16, 0, 0)

#define STAGE(KT_, BUF_) do { \
    GLDS(gA0 + (size_t)(KT_) * 64,             &qA[BUF_][wid * 2048]); \
    GLDS(gA0 + (size_t)(KT_) * 64 + 16 * DCOL, &qA[BUF_][wid * 2048 + 1024]); \
    GLDS(gB0 + (size_t)(KT_) * 64,             &qB[BUF_][wid * 2048]); \
    GLDS(gB0 + (size_t)(KT_) * 64 + 16 * DCOL, &qB[BUF_][wid * 2048 + 1024]); \
  } while (0)

__global__ __launch_bounds__(256, 3) void mmd_gemm_kernel(
    const s8* __restrict__ qp, const float* __restrict__ sqq,
    const float* __restrict__ colsum_rep, const double* __restrict__ sumsq_rep,
    float* __restrict__ slots, unsigned int* __restrict__ counter,
    float* __restrict__ out) {
  __shared__ __align__(16) s8 qA[3][8192];   // 3 x 8 KB
  __shared__ __align__(16) s8 qB[3][8192];   // 3 x 8 KB
  __shared__ float sqR[BM], sqC[BM];
  __shared__ double redd[4];
  __shared__ double sS;
  __shared__ float sGf;
  __shared__ float wpart[4];
  __shared__ int isLast;

  // bijective XCD swizzle (2080 % 8 == 0), then linear-index -> triangle (I<=J)
  int bid = blockIdx.x;
  int t6 = (bid & 7) * (NTILES / 8) + (bid >> 3);
  int I = 0, rem = t6;
  while (rem >= TT - I) { rem -= TT - I; ++I; }
  int J = I + rem;
  int rowStart = I * BM, colStart = J * BM;

  int tid = threadIdx.x;
  int lane = tid & 63, wid = tid >> 6;
  int wr = wid >> 1, wc = wid & 1;
  int r15 = lane & 15, kg = lane >> 4;

  // staging global src (dbl-row swizzle folded into per-lane source address)
  int u = (lane & 7) ^ (lane >> 3);
  int drow0 = wid * 16 + (lane >> 3);
  const s8* gA0 = qp + (size_t)(rowStart + drow0 * 2 + (u >> 2)) * DCOL + (u & 3) * 16;
  const s8* gB0 = qp + (size_t)(colStart + drow0 * 2 + (u >> 2)) * DCOL + (u & 3) * 16;

  // fragment read lane offset (bytes); 2 lanes/bank-quad = conflict-free
  int laneOff = ((r15 >> 1) * 128) +
                (((((r15 & 1) << 2) | kg) ^ ((r15 >> 1) & 7)) << 4);
  int aBase = wr * 4096 + laneOff;    // + m*1024
  int bBase = wc * 4096 + laneOff;    // + n*1024

  // ---- prologue: stage K-tiles 0,1; redundant per-block bandwidth (L2-hot, hidden
  // under staging flight). Kernel boundary = visibility, so plain loads suffice. ----
  STAGE(0, 0);
  STAGE(1, 1);
  if (tid < BM) sqR[tid] = sqq[rowStart + tid];
  else          sqC[tid - BM] = sqq[colStart + (tid - BM)];

  double sld = (wid == 0 && lane < NREP) ? sumsq_rep[lane] : 0.0;
  float c0 = 0.f, c1 = 0.f;
#pragma unroll
  for (int r = 0; r < NREP; ++r) {
    c0 += colsum_rep[r * DCOL + tid];
    c1 += colsum_rep[r * DCOL + tid + 256];
  }
  double scs = (double)c0 * c0 + (double)c1 * c1;
#pragma unroll
  for (int o = 32; o > 0; o >>= 1) scs += __shfl_down(scs, o);
  if (lane == 0) redd[wid] = scs;
  if (wid == 0) {
#pragma unroll
    for (int o = 4; o > 0; o >>= 1) sld += __shfl_down(sld, o);
    if (lane == 0) sS = sld;
  }

  // tile 0 ready (stage(1) stays in flight); all LDS writes drained
  asm volatile("s_waitcnt vmcnt(4) lgkmcnt(0)" ::: "memory");
  __builtin_amdgcn_s_barrier();

  if (tid == 0) {
    double C2 = redd[0] + redd[1] + redd[2] + redd[3];
    double n = (double)NROWS;
    double bwv = (2.0 * n * sS - 2.0 * C2) / (n * n - n);
    sGf = (float)(-1.0 / (16.0 * bwv));   // read in epilogue (ordered by K-loop barriers)
  }

  i32x4 acc[4][4];
#pragma unroll
  for (int m = 0; m < 4; ++m)
#pragma unroll
    for (int n = 0; n < 4; ++n) acc[m][n] = (i32x4){0, 0, 0, 0};

  // ---- main loop (R13-proven): read buf[kt%3] | stage kt+2 | MFMA | vmcnt(4) | barrier ----
#pragma unroll
  for (int kt = 0; kt < KT; ++kt) {
    const int buf = kt % 3;

    i32x4 a[4], b[4];
#pragma unroll
    for (int m = 0; m < 4; ++m)
      a[m] = *reinterpret_cast<const i32x4*>(&qA[buf][aBase + m * 1024]);
#pragma unroll
    for (int n = 0; n < 4; ++n)
      b[n] = *reinterpret_cast<const i32x4*>(&qB[buf][bBase + n * 1024]);

    if (kt + 2 < KT) STAGE(kt + 2, (kt + 2) % 3);

#pragma unroll
    for (int m = 0; m < 4; ++m)
#pragma unroll
      for (int n = 0; n < 4; ++n)
        acc[m][n] = __builtin_amdgcn_mfma_i32_16x16x64_i8(a[m], b[n], acc[m][n], 0, 0, 0);

    if (kt + 2 < KT) {
      asm volatile("s_waitcnt vmcnt(4)" ::: "memory");
      __builtin_amdgcn_s_barrier();
    } else if (kt + 1 < KT) {
      asm volatile("s_waitcnt vmcnt(0)" ::: "memory");
      __builtin_amdgcn_s_barrier();
    }
  }

  // ---- fused epilogue: l2 -> u + u^2 + u^4 + u^8 + u^16 ----
  float gf = sGf;
  float partial = 0.f;
  int rbase = (lane >> 4) * 4;
#pragma unroll
  for (int m = 0; m < 4; ++m) {
    float sr[4];
#pragma unroll
    for (int e = 0; e < 4; ++e) sr[e] = sqR[wr * 64 + m * 16 + rbase + e];
#pragma unroll
    for (int n = 0; n < 4; ++n) {
      float sc = sqC[wc * 64 + n * 16 + r15];
#pragma unroll
      for (int e = 0; e < 4; ++e) {
        float d = (float)acc[m][n][e] * INV_S2;   // exact (|dot| < 2^23)
        float l2v = sr[e] + sc - 2.f * d;
        float uu = __expf(gf * l2v);
        float u2 = uu * uu, u4 = u2 * u2, u8 = u4 * u4, u16v = u8 * u8;
        partial += uu + u2 + u4 + u8 + u16v;
      }
    }
  }
  float wsign = ((I == J) ? 1.f : 2.f) *
                (((rowStart < B_HALF) == (colStart < B_HALF)) ? 1.f : -1.f);
  partial *= wsign;
#pragma unroll
  for (int o = 32; o > 0; o >>= 1) partial += __shfl_down(partial, o);
  if (lane == 0) wpart[wid] = partial;
  __syncthreads();

  // ---- fused finalize (R8-proven, NO threadfence): coherent slot write, counter,
  // last-block atomic-load reduce ----
  if (tid == 0) {
    float bp = wpart[0] + wpart[1] + wpart[2] + wpart[3];
    atomicExch(&slots[bid], bp);
  }
  asm volatile("s_waitcnt vmcnt(0)" ::: "memory");  // slot write globally complete
  __syncthreads();
  if (tid == 0)
    isLast = ((atomicAdd(counter, 1u) % (unsigned)NTILES) == NTILES - 1);
  __syncthreads();
  if (isLast) {
    double s = 0.0;
    for (int i = tid; i < NTILES; i += 256)
      s += (double)atomicAdd(&slots[i], 0.f);       // atomic-load: coherent
#pragma unroll
    for (int o = 32; o > 0; o >>= 1) s += __shfl_down(s, o);
    if (lane == 0) redd[wid] = s;
    __syncthreads();
    if (tid == 0)
      out[0] = (float)((redd[0] + redd[1] + redd[2] + redd[3]) / (4096.0 * 4096.0));
  }
}

extern "C" void kernel_launch(void* const* d_in, const int* in_sizes, int n_in,
                              void* d_out, int out_size, void* d_ws, size_t ws_size,
                              hipStream_t stream) {
  const float* src = (const float*)d_in[0];
  const float* tgt = (const float*)d_in[1];
  char* ws = (char*)d_ws;

  float*        colsum_rep = (float*)(ws + 0);        // 8*512 f32 = 16 KB (zeroed)
  double*       sumsq_rep  = (double*)(ws + 16384);   // 8 f64 (zeroed)
  unsigned int* counter    = (unsigned int*)(ws + 16448);  // (zeroed)
  float*        sqq        = (float*)(ws + 20480);    // 8192 f32 (overwritten)
  float*        slots      = (float*)(ws + 53248);    // 2080 f32 (atomicExch overwrite)
  s8*           qp         = (s8*)(ws + 98304);       // 8192*512 i8 = 4.19 MB

  zero_kernel<<<1, 256, 0, stream>>>((uint4*)ws);     // zero 20480 B

  prep_kernel<<<PREP_BLOCKS, 256, 0, stream>>>(src, tgt, qp, sqq,
                                               colsum_rep, sumsq_rep);
  mmd_gemm_kernel<<<NTILES, 256, 0, stream>>>(qp, sqq, colsum_rep, sumsq_rep,
                                              slots, counter, (float*)d_out);
}

// Round 15
// 69.961 us; speedup vs baseline: 1.6334x; 1.6334x over previous
//
#include <hip/hip_runtime.h>
#include <stdint.h>

typedef signed char s8;
typedef int i32x4 __attribute__((ext_vector_type(4)));

#define B_HALF 4096
#define NROWS 8192
#define DCOL 512
#define BM 128
#define TT 64            // 8192/128
#define NTILES 2080      // TT*(TT+1)/2
#define KT 8             // 512 / 64 bytes per K-step
#define QSCALE 32.0f
#define INV_S2 (1.0f / 1024.0f)
#define PREP_BLOCKS (NROWS / 16)   // 512
#define NREP 8

// ---------- kernel Z: zero the 20.5 KB accumulator region ----------
__global__ void zero_kernel(uint4* __restrict__ p) {
  int t = threadIdx.x;
#pragma unroll
  for (int i = 0; i < 5; ++i)
    p[t + i * 256] = (uint4){0u, 0u, 0u, 0u};   // 5 * 256 * 16 B = 20480 B
}

// ---------- kernel A: quantize + sqq + 8-replica colsum/sumsq + last-block bandwidth ----------
__global__ __launch_bounds__(256) void prep_kernel(const float* __restrict__ src,
    const float* __restrict__ tgt, s8* __restrict__ qp,
    float* __restrict__ sqq, float* __restrict__ colsum_rep,
    double* __restrict__ sumsq_rep, unsigned int* __restrict__ counter,
    float* __restrict__ gf_out) {
  __shared__ float cs[4][DCOL];
  __shared__ double redd[4];
  __shared__ int lastFlag;
  int tid = threadIdx.x;
  int lane = tid & 63, wid = tid >> 6;
  float cpart[8] = {0.f,0.f,0.f,0.f,0.f,0.f,0.f,0.f};
  float myssq = 0.f;
  int row0 = blockIdx.x * 16;
#pragma unroll
  for (int r = 0; r < 4; ++r) {
    int row = row0 + r * 4 + wid;
    const float* x = (row < B_HALF) ? (src + (size_t)row * DCOL)
                                    : (tgt + (size_t)(row - B_HALF) * DCOL);
    float4 v0 = *reinterpret_cast<const float4*>(x + lane * 8);
    float4 v1 = *reinterpret_cast<const float4*>(x + lane * 8 + 4);
    float vals[8] = {v0.x, v0.y, v0.z, v0.w, v1.x, v1.y, v1.z, v1.w};
    union { s8 c[8]; uint2 u; } pu;
    int iq = 0;
#pragma unroll
    for (int q = 0; q < 8; ++q) {
      float f = vals[q];
      myssq += f * f;
      cpart[q] += f;
      int k = __float2int_rn(fminf(fmaxf(f * QSCALE, -127.f), 127.f));
      pu.c[q] = (s8)k;
      iq += k * k;
    }
    *reinterpret_cast<uint2*>(qp + (size_t)row * DCOL + lane * 8) = pu.u;
#pragma unroll
    for (int o = 32; o > 0; o >>= 1) iq += __shfl_down(iq, o);
    if (lane == 0) sqq[row] = (float)iq * INV_S2;   // exact: iq < 2^23
  }
  double dssq = (double)myssq;
#pragma unroll
  for (int o = 32; o > 0; o >>= 1) dssq += __shfl_down(dssq, o);
  if (lane == 0) redd[wid] = dssq;
#pragma unroll
  for (int q = 0; q < 8; ++q) cs[wid][lane * 8 + q] = cpart[q];
  __syncthreads();
  // 8-replica accumulation: atomic chains 512 -> 64 deep per address
  int rep = (blockIdx.x & (NREP - 1)) * DCOL;
  int c = tid;
  atomicAdd(&colsum_rep[rep + c],
            cs[0][c] + cs[1][c] + cs[2][c] + cs[3][c]);
  atomicAdd(&colsum_rep[rep + c + 256],
            cs[0][c + 256] + cs[1][c + 256] + cs[2][c + 256] + cs[3][c + 256]);
  if (tid == 0)
    atomicAdd(&sumsq_rep[blockIdx.x & (NREP - 1)],
              redd[0] + redd[1] + redd[2] + redd[3]);

  // ---- last block computes bandwidth (atomics-only cross-block reads) ----
  asm volatile("s_waitcnt vmcnt(0)" ::: "memory");
  __syncthreads();
  if (tid == 0)
    lastFlag = ((atomicAdd(counter, 1u) % (unsigned)PREP_BLOCKS) == PREP_BLOCKS - 1);
  __syncthreads();
  if (lastFlag) {
    float c0 = 0.f, c1 = 0.f;
#pragma unroll
    for (int r = 0; r < NREP; ++r) {
      c0 += atomicAdd(&colsum_rep[r * DCOL + tid], 0.f);        // atomic-load
      c1 += atomicAdd(&colsum_rep[r * DCOL + tid + 256], 0.f);
    }
    double scs = (double)c0 * c0 + (double)c1 * c1;
#pragma unroll
    for (int o = 32; o > 0; o >>= 1) scs += __shfl_down(scs, o);
    if (lane == 0) redd[wid] = scs;
    __syncthreads();
    if (tid == 0) {
      double C2 = redd[0] + redd[1] + redd[2] + redd[3];
      double S = 0.0;
#pragma unroll
      for (int r = 0; r < NREP; ++r) S += atomicAdd(&sumsq_rep[r], 0.0);
      double n = (double)NROWS;
      double bwv = (2.0 * n * S - 2.0 * C2) / (n * n - n);
      gf_out[0] = (float)(-1.0 / (16.0 * bwv));
    }
  }
}

// ---------- kernel B: 128x128 triangle i8 MFMA Gram, BK=64 dbl-row,
// TRIPLE-buffered with counted vmcnt (R13-proven, byte-identical; NO finalize tail) ----------
#define GLDS(gptr, lptr) __builtin_amdgcn_global_load_lds( \
    (const __attribute__((address_space(1))) void*)(gptr), \
    (__attribute__((address_space(3))) void*)(lptr), 16, 0, 0)

#define STAGE(KT_, BUF_) do { \
    GLDS(gA0 + (size_t)(KT_) * 64,             &qA[BUF_][wid * 2048]); \
    GLDS(gA0 + (size_t)(KT_) * 64 + 16 * DCOL, &qA[BUF_][wid * 2048 + 1024]); \
    GLDS(gB0 + (size_t)(KT_) * 64,             &qB[BUF_][wid * 2048]); \
    GLDS(gB0 + (size_t)(KT_) * 64 + 16 * DCOL, &qB[BUF_][wid * 2048 + 1024]); \
  } while (0)

__global__ __launch_bounds__(256, 3) void mmd_gemm_kernel(
    const s8* __restrict__ qp, const float* __restrict__ sqq,
    const float* __restrict__ gf_ptr, float* __restrict__ partials) {
  __shared__ __align__(16) s8 qA[3][8192];   // 3 x 8 KB
  __shared__ __align__(16) s8 qB[3][8192];   // 3 x 8 KB
  __shared__ float sqR[BM], sqC[BM];

  // bijective XCD swizzle (2080 % 8 == 0), then linear-index -> triangle (I<=J)
  int bid = blockIdx.x;
  int t6 = (bid & 7) * (NTILES / 8) + (bid >> 3);
  int I = 0, rem = t6;
  while (rem >= TT - I) { rem -= TT - I; ++I; }
  int J = I + rem;
  int rowStart = I * BM, colStart = J * BM;

  int tid = threadIdx.x;
  int lane = tid & 63, wid = tid >> 6;
  int wr = wid >> 1, wc = wid & 1;
  int r15 = lane & 15, kg = lane >> 4;

  // staging global src (dbl-row swizzle folded into per-lane source address)
  int u = (lane & 7) ^ (lane >> 3);
  int drow0 = wid * 16 + (lane >> 3);
  const s8* gA0 = qp + (size_t)(rowStart + drow0 * 2 + (u >> 2)) * DCOL + (u & 3) * 16;
  const s8* gB0 = qp + (size_t)(colStart + drow0 * 2 + (u >> 2)) * DCOL + (u & 3) * 16;

  // fragment read lane offset (bytes); 2 lanes/bank-quad = conflict-free
  int laneOff = ((r15 >> 1) * 128) +
                (((((r15 & 1) << 2) | kg) ^ ((r15 >> 1) & 7)) << 4);
  int aBase = wr * 4096 + laneOff;    // + m*1024
  int bBase = wc * 4096 + laneOff;    // + n*1024

  // ---- prologue: stage K-tiles 0,1; sq/gf loads overlap staging ----
  STAGE(0, 0);
  STAGE(1, 1);
  if (tid < BM) sqR[tid] = sqq[rowStart + tid];
  else          sqC[tid - BM] = sqq[colStart + (tid - BM)];
  float gf = gf_ptr[0];
  asm volatile("s_waitcnt vmcnt(4) lgkmcnt(0)" ::: "memory");
  __builtin_amdgcn_s_barrier();

  i32x4 acc[4][4];
#pragma unroll
  for (int m = 0; m < 4; ++m)
#pragma unroll
    for (int n = 0; n < 4; ++n) acc[m][n] = (i32x4){0, 0, 0, 0};

  // ---- main loop: read buf[kt%3] | stage kt+2 | MFMA | vmcnt(4) | barrier ----
#pragma unroll
  for (int kt = 0; kt < KT; ++kt) {
    const int buf = kt % 3;

    i32x4 a[4], b[4];
#pragma unroll
    for (int m = 0; m < 4; ++m)
      a[m] = *reinterpret_cast<const i32x4*>(&qA[buf][aBase + m * 1024]);
#pragma unroll
    for (int n = 0; n < 4; ++n)
      b[n] = *reinterpret_cast<const i32x4*>(&qB[buf][bBase + n * 1024]);

    if (kt + 2 < KT) STAGE(kt + 2, (kt + 2) % 3);

#pragma unroll
    for (int m = 0; m < 4; ++m)
#pragma unroll
      for (int n = 0; n < 4; ++n)
        acc[m][n] = __builtin_amdgcn_mfma_i32_16x16x64_i8(a[m], b[n], acc[m][n], 0, 0, 0);

    if (kt + 2 < KT) {
      asm volatile("s_waitcnt vmcnt(4)" ::: "memory");
      __builtin_amdgcn_s_barrier();
    } else if (kt + 1 < KT) {
      asm volatile("s_waitcnt vmcnt(0)" ::: "memory");
      __builtin_amdgcn_s_barrier();
    }
  }

  // ---- fused epilogue: l2 -> u + u^2 + u^4 + u^8 + u^16 ----
  float partial = 0.f;
  int rbase = (lane >> 4) * 4;
#pragma unroll
  for (int m = 0; m < 4; ++m) {
    float sr[4];
#pragma unroll
    for (int e = 0; e < 4; ++e) sr[e] = sqR[wr * 64 + m * 16 + rbase + e];
#pragma unroll
    for (int n = 0; n < 4; ++n) {
      float sc = sqC[wc * 64 + n * 16 + r15];
#pragma unroll
      for (int e = 0; e < 4; ++e) {
        float d = (float)acc[m][n][e] * INV_S2;   // exact (|dot| < 2^23)
        float l2v = sr[e] + sc - 2.f * d;
        float uu = __expf(gf * l2v);
        float u2 = uu * uu, u4 = u2 * u2, u8 = u4 * u4, u16v = u8 * u8;
        partial += uu + u2 + u4 + u8 + u16v;
      }
    }
  }
  float wsign = ((I == J) ? 1.f : 2.f) *
                (((rowStart < B_HALF) == (colStart < B_HALF)) ? 1.f : -1.f);
  partial *= wsign;
#pragma unroll
  for (int o = 32; o > 0; o >>= 1) partial += __shfl_down(partial, o);
  if (lane == 0) partials[bid * 4 + wid] = partial;   // plain store; no fence/atomic
}

// ---------- kernel C: deterministic finalize (separate launch = coherent reads) ----------
__global__ void finalize_kernel(const float* __restrict__ partials,
                                float* __restrict__ out) {
  __shared__ double red[256];
  int tid = threadIdx.x;
  double s = 0.0;
  for (int i = tid; i < NTILES * 4; i += 256) s += (double)partials[i];
  red[tid] = s;
  __syncthreads();
  for (int o = 128; o > 0; o >>= 1) {
    if (tid < o) red[tid] += red[tid + o];
    __syncthreads();
  }
  if (tid == 0) out[0] = (float)(red[0] / (4096.0 * 4096.0));
}

extern "C" void kernel_launch(void* const* d_in, const int* in_sizes, int n_in,
                              void* d_out, int out_size, void* d_ws, size_t ws_size,
                              hipStream_t stream) {
  const float* src = (const float*)d_in[0];
  const float* tgt = (const float*)d_in[1];
  char* ws = (char*)d_ws;

  float*        colsum_rep = (float*)(ws + 0);        // 8*512 f32 = 16 KB (zeroed)
  double*       sumsq_rep  = (double*)(ws + 16384);   // 8 f64 (zeroed)
  unsigned int* counter    = (unsigned int*)(ws + 16448);  // (zeroed)
  float*        gfp        = (float*)(ws + 16452);
  float*        sqq        = (float*)(ws + 20480);    // 8192 f32
  float*        partials   = (float*)(ws + 53248);    // 2080*4 f32
  s8*           qp         = (s8*)(ws + 98304);       // 8192*512 i8 = 4.19 MB

  zero_kernel<<<1, 256, 0, stream>>>((uint4*)ws);     // zero 20480 B

  prep_kernel<<<PREP_BLOCKS, 256, 0, stream>>>(src, tgt, qp, sqq, colsum_rep,
                                               sumsq_rep, counter, gfp);
  mmd_gemm_kernel<<<NTILES, 256, 0, stream>>>(qp, sqq, gfp, partials);
  finalize_kernel<<<1, 256, 0, stream>>>(partials, (float*)d_out);
}